// Round 2
// baseline (7004.465 us; speedup 1.0000x reference)
//
#include <hip/hip_runtime.h>
#include <hip/hip_cooperative_groups.h>

namespace cg = cooperative_groups;

typedef __bf16 bf16x8 __attribute__((ext_vector_type(8)));
typedef float  f32x4  __attribute__((ext_vector_type(4)));
typedef unsigned short u16;
typedef unsigned int   u32;
typedef u16 u16x8 __attribute__((ext_vector_type(8)));

#define TT 512
#define BB 32
#define DD 1024

// ws layout (bytes)
#define WS_Z  0            // Z f32 [16384][2048] = 134217728 B
#define WS_HB 134217728    // h ping-pong hi/lo bf16: 2*2*32*1024*2 = 262144 B

static __device__ __forceinline__ u16 f2b(float f){
  u32 u = __builtin_bit_cast(u32, f);
  u32 r = (u + 0x7fffu + ((u>>16)&1u)) >> 16;
  return (u16)r;
}
static __device__ __forceinline__ float b2f(u16 h){
  return __builtin_bit_cast(float, (u32)h<<16);
}

#define GLD_LDS16(g, l) \
  __builtin_amdgcn_global_load_lds( \
      (__attribute__((address_space(1))) void*)(uintptr_t)(g), \
      (__attribute__((address_space(3))) void*)(l), 16, 0, 0)

#define MFMA16(a,b,c) __builtin_amdgcn_mfma_f32_16x16x32_bf16(a,b,c,0,0,0)

// ---- pre-GEMM (3-term split): Z[m][n] = sum_k x[m][k]*W[n][k], f32 out -----
// 128x128 tile, BK=64, 4 waves; A,B reg-staged from f32 with hi/lo split,
// swizzled LDS writes (XOR (row&7)<<4 within 128B row).
__global__ __launch_bounds__(256) void k_gemm3(const float* __restrict__ X,
    const float* __restrict__ Wa, const float* __restrict__ Wx,
    float* __restrict__ Z){
  __shared__ u16 Ahi[128*64];
  __shared__ u16 Alo[128*64];
  __shared__ u16 Bhi[128*64];
  __shared__ u16 Blo[128*64];
  int id  = blockIdx.x;
  int swz = (id & 7)*256 + (id>>3);
  int mblk = swz>>4, nblk = swz&15;
  const float* W = (nblk < 8) ? Wa : Wx;
  int n0 = (nblk&7)*128;
  int m0 = mblk*128;
  int tid = threadIdx.x, lane = tid&63, w = tid>>6;
  int wm = w>>1, wn = w&1;
  int sr = tid>>1, sh = tid&1;          // staging: row 0..127, k-half

  f32x4 acc[4][4];
  #pragma unroll
  for (int i=0;i<4;i++)
    #pragma unroll
    for (int j=0;j<4;j++) acc[i][j] = (f32x4){0.f,0.f,0.f,0.f};

  for (int kb = 0; kb < DD; kb += 64){
    const float* sa  = X + (size_t)(m0+sr)*DD + kb + sh*32;
    const float* sbp = W + (size_t)(n0+sr)*DD + kb + sh*32;
    int rswz = (sr&7)<<4;
    #pragma unroll
    for (int g=0; g<4; g++){
      float4 va0 = ((const float4*)sa)[g*2];
      float4 va1 = ((const float4*)sa)[g*2+1];
      float4 vb0 = ((const float4*)sbp)[g*2];
      float4 vb1 = ((const float4*)sbp)[g*2+1];
      float fa[8] = {va0.x,va0.y,va0.z,va0.w,va1.x,va1.y,va1.z,va1.w};
      float fb[8] = {vb0.x,vb0.y,vb0.z,vb0.w,vb1.x,vb1.y,vb1.z,vb1.w};
      u16x8 ah, al, bh, bl;
      #pragma unroll
      for (int j=0;j<8;j++){
        u16 ha = f2b(fa[j]); ah[j] = ha; al[j] = f2b(fa[j] - b2f(ha));
        u16 hb = f2b(fb[j]); bh[j] = hb; bl[j] = f2b(fb[j] - b2f(hb));
      }
      int off = sr*128 + ((sh*64 + g*16) ^ rswz);
      *(u16x8*)((char*)Ahi + off) = ah;
      *(u16x8*)((char*)Alo + off) = al;
      *(u16x8*)((char*)Bhi + off) = bh;
      *(u16x8*)((char*)Blo + off) = bl;
    }
    __syncthreads();
    #pragma unroll
    for (int ks=0; ks<2; ks++){
      int kby = ks*64 + ((lane>>4)<<4);
      bf16x8 ahf[4], alf[4], bhf[4], blf[4];
      #pragma unroll
      for (int mi=0;mi<4;mi++){
        int row = wm*64 + mi*16 + (lane&15);
        int ao = row*128 + (kby ^ ((row&7)<<4));
        ahf[mi] = *(const bf16x8*)((const char*)Ahi + ao);
        alf[mi] = *(const bf16x8*)((const char*)Alo + ao);
      }
      #pragma unroll
      for (int ni=0;ni<4;ni++){
        int row = wn*64 + ni*16 + (lane&15);
        int bo = row*128 + (kby ^ ((row&7)<<4));
        bhf[ni] = *(const bf16x8*)((const char*)Bhi + bo);
        blf[ni] = *(const bf16x8*)((const char*)Blo + bo);
      }
      #pragma unroll
      for (int mi=0;mi<4;mi++)
        #pragma unroll
        for (int ni=0;ni<4;ni++){
          acc[mi][ni] = MFMA16(ahf[mi], bhf[ni], acc[mi][ni]);
          acc[mi][ni] = MFMA16(ahf[mi], blf[ni], acc[mi][ni]);
          acc[mi][ni] = MFMA16(alf[mi], bhf[ni], acc[mi][ni]);
        }
    }
    __syncthreads();
  }

  #pragma unroll
  for (int mi=0;mi<4;mi++){
    #pragma unroll
    for (int ni=0;ni<4;ni++){
      int colz = nblk*128 + wn*64 + ni*16 + (lane&15);
      #pragma unroll
      for (int q=0;q<4;q++){
        int rowm = m0 + wm*64 + mi*16 + ((lane>>4)<<2) + q;
        Z[(size_t)rowm*2048 + colz] = acc[mi][ni][q];
      }
    }
  }
}

// ---- init: hout[0] = h0 (f32), hbf buf0 = (hi,lo) of h0 --------------------
__global__ void k_init(const float* __restrict__ h0, float* __restrict__ hout0,
                       u16* __restrict__ hbf){
  int i = blockIdx.x*blockDim.x + threadIdx.x;
  if (i < BB*DD){
    float v = h0[i];
    hout0[i] = v;
    u16 hh = f2b(v);
    hbf[i] = hh;
    hbf[BB*DD + i] = f2b(v - b2f(hh));
  }
}

// ---- recurrence: cooperative, 32 wgs x 512 thr (8 waves) -------------------
// wave w = kh*4 + wm*2 + wn :  kh = K-half, wm = row-half(b), wn = col-half(e)
// Wh hi/lo fragments resident in VGPRs (per wave: 16 cols x 512 k).
// h staged per step into LDS as hi/lo bf16 (gld_lds, pre-swizzled source).
// h chain kept f32 in registers; split-K partials reduced via LDS.
__global__ __launch_bounds__(512) void k_recur2(
    const float* __restrict__ Z, const float* __restrict__ Wh,
    const float* __restrict__ h0,
    const float* __restrict__ balpha, const float* __restrict__ bvec,
    float* __restrict__ out0,   // [512][32][1024]
    float* __restrict__ hout,   // [513][32][1024]
    u16* __restrict__ hbf){     // [2][2][32][1024] (ping/pong, hi/lo)
  __shared__ u16 Hhi[BB*DD];    // 64KB, rows=b (2048B), XOR (row&7)<<4
  __shared__ u16 Hlo[BB*DD];    // 64KB
  __shared__ f32x4 Red[4][64];  // 4KB split-K exchange
  cg::grid_group grid = cg::this_grid();

  int blk = blockIdx.x, e0 = blk*32;
  int tid = threadIdx.x, lane = tid&63, w = tid>>6;
  int kh = w>>2, wm = (w>>1)&1, wn = w&1;

  // preload Wh fragments (hi/lo) into VGPRs: col = e0+wn*16+(lane&15),
  // k = kh*512 + ks*32 + (lane>>4)*8 + j
  bf16x8 wfh[16], wfl[16];
  {
    const float* wrow = Wh + (size_t)(e0 + wn*16 + (lane&15))*DD
                           + kh*512 + ((lane>>4)<<3);
    #pragma unroll
    for (int ks=0; ks<16; ks++){
      float4 a = ((const float4*)(wrow + ks*32))[0];
      float4 b = ((const float4*)(wrow + ks*32))[1];
      float f[8] = {a.x,a.y,a.z,a.w,b.x,b.y,b.z,b.w};
      u16x8 uh, ul;
      #pragma unroll
      for (int j=0;j<8;j++){
        u16 hh = f2b(f[j]);
        uh[j] = hh;
        ul[j] = f2b(f[j] - b2f(hh));
      }
      wfh[ks] = __builtin_bit_cast(bf16x8, uh);
      wfl[ks] = __builtin_bit_cast(bf16x8, ul);
    }
  }

  int el = e0 + wn*16 + (lane&15);
  float ba = balpha[el], bb = bvec[el];
  float hc[4]  = {0.f,0.f,0.f,0.f};
  float axr[4] = {0.f,0.f,0.f,0.f};
  float wxr[4] = {0.f,0.f,0.f,0.f};
  if (kh == 0){
    #pragma unroll
    for (int q=0;q<4;q++){
      int b = wm*16 + ((lane>>4)<<2) + q;
      hc[q]  = h0[b*DD + el];
      axr[q] = Z[(size_t)b*2048 + el];
      wxr[q] = Z[(size_t)b*2048 + DD + el];
    }
  }

  for (int t=0;t<TT;t++){
    // stage h_prev hi/lo -> LDS (linear dest, inverse-swizzled source)
    const char* shi = (const char*)(hbf + (size_t)(t&1)*2*BB*DD);
    const char* slo = shi + (size_t)BB*DD*2;
    #pragma unroll
    for (int r=0;r<8;r++){
      int sb = r*8192 + w*1024;
      int s  = sb + (lane<<4);
      int row = s>>11, cp = s&2047;
      int c = cp ^ ((row&7)<<4);
      GLD_LDS16(shi + row*2048 + c, (char*)Hhi + sb);
      GLD_LDS16(slo + row*2048 + c, (char*)Hlo + sb);
    }
    // current step Z, prefetch next step
    float axc[4], wxc[4];
    if (kh == 0){
      #pragma unroll
      for (int q=0;q<4;q++){ axc[q]=axr[q]; wxc[q]=wxr[q]; }
      if (t < TT-1){
        #pragma unroll
        for (int q=0;q<4;q++){
          int b = wm*16 + ((lane>>4)<<2) + q;
          size_t zi = ((size_t)(t+1)*BB + b)*2048 + el;
          axr[q] = Z[zi]; wxr[q] = Z[zi + DD];
        }
      }
    } else {
      #pragma unroll
      for (int q=0;q<4;q++){ axc[q]=0.f; wxc[q]=0.f; }
    }
    __syncthreads();   // drains gld_lds writes

    // 3-chain MFMA over this wave's K-half
    f32x4 a0 = (f32x4){0.f,0.f,0.f,0.f};
    f32x4 a1 = (f32x4){0.f,0.f,0.f,0.f};
    f32x4 a2 = (f32x4){0.f,0.f,0.f,0.f};
    int ra    = wm*16 + (lane&15);
    int rbase = ra*2048;
    int rsw   = (ra&7)<<4;
    int kb0   = kh*1024 + ((lane>>4)<<4);
    #pragma unroll
    for (int ks=0; ks<16; ks++){
      int off = rbase + ((kb0 + ks*64) ^ rsw);
      bf16x8 ahi = *(const bf16x8*)((const char*)Hhi + off);
      bf16x8 alo = *(const bf16x8*)((const char*)Hlo + off);
      a0 = MFMA16(ahi, wfh[ks], a0);
      a1 = MFMA16(ahi, wfl[ks], a1);
      a2 = MFMA16(alo, wfh[ks], a2);
    }
    f32x4 acc = a0 + a1 + a2;
    if (kh == 1){ Red[wm*2+wn][lane] = acc; }
    __syncthreads();

    if (kh == 0){
      acc += Red[wm*2+wn][lane];
      u16* dhi = hbf + (size_t)((t+1)&1)*2*BB*DD;
      u16* dlo = dhi + BB*DD;
      #pragma unroll
      for (int q=0;q<4;q++){
        int b = wm*16 + ((lane>>4)<<2) + q;
        float ax = axc[q] + ba;
        float alpha = 1.f/(1.f + expf(-ax));
        float v = tanhf(acc[q] + wxc[q] + bb);
        float h = hc[q] + alpha*v;
        hc[q] = h;
        size_t oi = (size_t)t*(BB*DD) + (size_t)b*DD + el;
        float sg = 1.f/(1.f + expf(-h));
        out0[oi] = h*h*sg;          // h * silu(h)
        hout[oi + BB*DD] = h;       // h[t+1]
        u16 hh = f2b(h);
        dhi[b*DD + el] = hh;
        dlo[b*DD + el] = f2b(h - b2f(hh));
      }
    }
    __threadfence();
    grid.sync();
  }
}

// ---- launch ----------------------------------------------------------------
extern "C" void kernel_launch(void* const* d_in, const int* in_sizes, int n_in,
                              void* d_out, int out_size, void* d_ws, size_t ws_size,
                              hipStream_t stream){
  (void)in_sizes; (void)n_in; (void)out_size; (void)ws_size;
  const float* x   = (const float*)d_in[0];
  const float* h0  = (const float*)d_in[1];
  const float* Wa  = (const float*)d_in[2];
  const float* bal = (const float*)d_in[3];
  const float* Whf = (const float*)d_in[4];
  const float* Wxf = (const float*)d_in[5];
  const float* bv  = (const float*)d_in[6];

  char* ws = (char*)d_ws;
  float* Zb  = (float*)(ws + WS_Z);
  u16*   hbf = (u16*)(ws + WS_HB);

  float* out0 = (float*)d_out;                       // [512][32][1024]
  float* hout = (float*)d_out + (size_t)TT*BB*DD;    // [513][32][1024]

  k_gemm3<<<2048, 256, 0, stream>>>(x, Wa, Wxf, Zb);
  k_init<<<(BB*DD+255)/256, 256, 0, stream>>>(h0, hout, hbf);

  void* args[] = {(void*)&Zb, (void*)&Whf, (void*)&h0, (void*)&bal, (void*)&bv,
                  (void*)&out0, (void*)&hout, (void*)&hbf};
  hipLaunchCooperativeKernel((const void*)k_recur2, dim3(32), dim3(512),
                             args, 0, stream);
}